// Round 7
// baseline (555.192 us; speedup 1.0000x reference)
//
#include <hip/hip_runtime.h>
#include <stdint.h>

#define DEV static __device__ __forceinline__

typedef __bf16 bf16x8 __attribute__((ext_vector_type(8)));
typedef float f32x4 __attribute__((ext_vector_type(4)));
typedef float f32x16 __attribute__((ext_vector_type(16)));
typedef uint32_t u32x4 __attribute__((ext_vector_type(4)));

typedef const __attribute__((address_space(1))) void* as1cp;
typedef __attribute__((address_space(3))) void* as3p;

DEV uint32_t pk2(float lo, float hi) {       // packed bf16 pair (RNE casts)
  uint16_t a = __builtin_bit_cast(uint16_t, (__bf16)lo);
  uint16_t b = __builtin_bit_cast(uint16_t, (__bf16)hi);
  return (uint32_t)a | ((uint32_t)b << 16);
}
DEV uint16_t bfc(float f) { return __builtin_bit_cast(uint16_t, (__bf16)f); }
DEV float bf2f(uint32_t h) { return __builtin_bit_cast(float, h << 16); }

DEV void gll16(const void* g, void* l) {
  __builtin_amdgcn_global_load_lds((as1cp)g, (as3p)l, 16, 0, 0);
}

// ---------------------------------------------------------------------------
// Projection v5 (UNCHANGED from R6): out = X @ W^T + b, bf16 MFMA.
// BM=128, BN=128, grid 128x2x3 = 768 blocks = 3 blocks/CU, 256 thr (4 waves).
// z=0 -> q (scaled log2(e)/16), z=1 -> k, z=2 -> v TRANSPOSED [b][d][s].
// ---------------------------------------------------------------------------
__global__ __launch_bounds__(256, 3) void proj_kernel(
    const float* __restrict__ xq, const float* __restrict__ xk, const float* __restrict__ xv,
    const float* __restrict__ wq, const float* __restrict__ wk, const float* __restrict__ wv,
    const float* __restrict__ bq, const float* __restrict__ bk, const float* __restrict__ bv,
    uint16_t* __restrict__ qo, uint16_t* __restrict__ ko, uint16_t* __restrict__ vo)
{
  const int z = blockIdx.z;
  const float* X  = (z == 0) ? xq : (z == 1) ? xk : xv;
  const float* W  = (z == 0) ? wq : (z == 1) ? wk : wv;
  const float* Bi = (z == 0) ? bq : (z == 1) ? bk : bv;

  const int tid = threadIdx.x;
  const int lane = tid & 63;
  const int w = tid >> 6;
  const int wm = w >> 1, wn = w & 1;
  const int l15 = lane & 15, g = lane >> 4;
  const int m0 = blockIdx.x * 128;
  const int n0 = blockIdx.y * 128;

  __shared__ uint16_t sA[128 * 64];
  __shared__ uint16_t sB[128 * 64];

  const int srow = tid >> 4;
  const int scu  = tid & 15;
  const float* Abase = X + (size_t)(m0 + srow) * 1024 + scu * 4;
  const float* Wbase = W + (size_t)(n0 + srow) * 1024 + scu * 4;
  uint32_t sdst[8];
  #pragma unroll
  for (int r = 0; r < 8; ++r) {
    uint32_t row = (uint32_t)(r * 16 + srow);
    sdst[r] = row * 128 + (((uint32_t)scu * 8) ^ ((row & 7) << 4));
  }

  f32x4 acc[4][4];
  #pragma unroll
  for (int i = 0; i < 4; ++i)
    #pragma unroll
    for (int j = 0; j < 4; ++j) { f32x4 zz = {0.f, 0.f, 0.f, 0.f}; acc[i][j] = zz; }

  float4 a4[8];
  #pragma unroll
  for (int r = 0; r < 8; ++r)
    a4[r] = *(const float4*)(Abase + (size_t)r * 16384);

  for (int kt = 0; kt < 16; ++kt) {
    if (kt) __syncthreads();
    #pragma unroll
    for (int r = 0; r < 8; ++r) {
      uint2 p; p.x = pk2(a4[r].x, a4[r].y); p.y = pk2(a4[r].z, a4[r].w);
      *(uint2*)((char*)sA + sdst[r]) = p;
    }
    {
      float4 w4[8];
      #pragma unroll
      for (int r = 0; r < 8; ++r)
        w4[r] = *(const float4*)(Wbase + (size_t)r * 16384 + kt * 64);
      #pragma unroll
      for (int r = 0; r < 8; ++r) {
        uint2 p; p.x = pk2(w4[r].x, w4[r].y); p.y = pk2(w4[r].z, w4[r].w);
        *(uint2*)((char*)sB + sdst[r]) = p;
      }
    }
    __syncthreads();
    if (kt < 15) {
      #pragma unroll
      for (int r = 0; r < 8; ++r)
        a4[r] = *(const float4*)(Abase + (size_t)r * 16384 + (kt + 1) * 64);
    }
    #pragma unroll
    for (int ks = 0; ks < 2; ++ks) {
      bf16x8 fa[4], fb[4];
      #pragma unroll
      for (int f = 0; f < 4; ++f) {
        uint32_t row = wm * 64 + 16 * f + l15;
        fa[f] = *(const bf16x8*)((char*)sA + row * 128 +
                 (((uint32_t)(ks * 64 + g * 16)) ^ ((row & 7) << 4)));
      }
      #pragma unroll
      for (int f = 0; f < 4; ++f) {
        uint32_t row = wn * 64 + 16 * f + l15;
        fb[f] = *(const bf16x8*)((char*)sB + row * 128 +
                 (((uint32_t)(ks * 64 + g * 16)) ^ ((row & 7) << 4)));
      }
      #pragma unroll
      for (int fm = 0; fm < 4; ++fm)
        #pragma unroll
        for (int fn = 0; fn < 4; ++fn)
          acc[fm][fn] = __builtin_amdgcn_mfma_f32_16x16x32_bf16(fa[fm], fb[fn], acc[fm][fn], 0, 0, 0);
    }
  }

  #pragma unroll
  for (int fn = 0; fn < 4; ++fn) {
    const int n = n0 + wn * 64 + 16 * fn + l15;
    const float bias = Bi[n];
    #pragma unroll
    for (int fm = 0; fm < 4; ++fm) {
      const int mg = m0 + wm * 64 + 16 * fm + 4 * g;
      if (z == 0) {
        #pragma unroll
        for (int r = 0; r < 4; ++r)
          qo[(size_t)(mg + r) * 256 + n] =
              bfc((acc[fm][fn][r] + bias) * 0.09016844f);   // log2(e)/16
      } else if (z == 1) {
        #pragma unroll
        for (int r = 0; r < 4; ++r)
          ko[(size_t)(mg + r) * 256 + n] = bfc(acc[fm][fn][r] + bias);
      } else {
        uint2 pv;
        pv.x = pk2(acc[fm][fn][0] + bias, acc[fm][fn][1] + bias);
        pv.y = pk2(acc[fm][fn][2] + bias, acc[fm][fn][3] + bias);
        *(uint2*)(vo + (((size_t)(mg >> 12)) << 20) + (((size_t)n) << 12) + (mg & 4095)) = pv;
      }
    }
  }
}

// ---------------------------------------------------------------------------
// Flash attention v7: swapped-operand 32x32 MFMA, in-register softmax (T12).
// 512 blocks x 128 thr (2 waves). Wave = kv-half; QBLK=32 q-cols per block.
//   QK^T = mfma(K-frag, Q-frag): C col = lane&31 = q  -> lane owns q-column;
//   kv in 16 regs -> max/sum = 15 in-lane ops + 1 shfl_xor(32).
//   PV as O^T = mfma(V^T-frag, P^T-frag): P^T is lane-local (8 pk2 + 8 shfl);
//   rescale scalar per lane. V^T read DIRECT from L2 (2MB/batch, XCD-pinned).
// K staged in LDS (2 x 16KB, 5-bit XOR swizzle, gll16 pre-swizzled source),
// single-buffered; 33KB LDS -> 4 blocks/CU cover the stage barriers.
// Flash-merge of halves through swizzled LDS transpose -> coalesced stores.
// ---------------------------------------------------------------------------
__global__ __launch_bounds__(128, 2) void attn_kernel(
    const uint16_t* __restrict__ qg, const uint16_t* __restrict__ kg,
    const uint16_t* __restrict__ vg, float* __restrict__ out)
{
  extern __shared__ char smem[];   // K: 2 x 16KB; epilogue aliases + 512B m/l

  const int bid = blockIdx.x;
  const int xcd = bid & 7, slot = bid >> 3;         // 512 blocks: slot 0..63
  const int batch = xcd >> 1;                       // batch pinned to XCD pair
  const int q0 = ((xcd & 1) * 64 + slot) * 32;

  const int tid = threadIdx.x;
  const int lane = tid & 63;
  const int hv = tid >> 6;                 // wave index = kv half
  const int l31 = lane & 31, hh = lane >> 5;
  const size_t rowb = (size_t)batch * 4096;

  // Q B-frags: lane holds Q[q=l31][k = 16s + 8*hh + 0..7], s=0..15
  bf16x8 qf[16];
  {
    const char* qp = (const char*)qg + (rowb + q0 + l31) * 512 + hh * 16;
    #pragma unroll
    for (int s = 0; s < 16; ++s) qf[s] = *(const bf16x8*)(qp + s * 32);
  }

  f32x16 o[8];
  #pragma unroll
  for (int i = 0; i < 8; ++i) { f32x16 zz = {}; o[i] = zz; }
  float mrow = -1e30f, lrow = 0.f;

  const char* kgb = (const char*)kg + rowb * 512;                   // K [s][256]
  const char* vgb = (const char*)vg + (size_t)batch * 2097152;      // V^T [d][4096]

  // K staging: 32KB/tile (2 halves x 32 rows x 512B), 128 thr x 16 gll16.
  // dest slot L=(r*128+tid)*16 linear; source col pre-swizzled ^(row<<4).
  auto STAGE = [&](int t) {
    #pragma unroll
    for (int r = 0; r < 16; ++r) {
      const int half = r >> 3;
      uint32_t row = (uint32_t)(4 * r + (tid >> 5)) & 31u;
      uint32_t colsw = (((uint32_t)(tid & 31)) * 16u) ^ (row << 4);
      const char* src = kgb + (((size_t)(half * 2048 + t * 32) + row) << 9) + colsw;
      gll16(src, smem + (size_t)(r * 128 + tid) * 16);
    }
  };

  STAGE(0);
  __syncthreads();

  const char* Kb = smem + hv * 16384;
  const char* vLane = vgb + (size_t)l31 * 8192 + hv * 4096 + hh * 16;
  const uint32_t csw = (uint32_t)l31 << 4;

  for (int t = 0; t < 64; ++t) {
    // ---- S^T = K Q^T : lane owns q-col l31; kv rows in 16 regs
    f32x16 s4 = {};
    const char* kr = Kb + (uint32_t)l31 * 512;
    #pragma unroll
    for (int s = 0; s < 16; ++s) {
      bf16x8 kf = *(const bf16x8*)(kr + (((uint32_t)(32 * s + 16 * hh)) ^ csw));
      s4 = __builtin_amdgcn_mfma_f32_32x32x16_bf16(kf, qf[s], s4, 0, 0, 0);
    }

    // ---- in-register online softmax (exp2 domain; scale folded into q)
    float pm = s4[0];
    #pragma unroll
    for (int r = 1; r < 16; ++r) pm = fmaxf(pm, s4[r]);
    pm = fmaxf(pm, __shfl_xor(pm, 32, 64));
    if (!__all(pm <= mrow + 8.f)) {              // defer-max (T13, THR=8)
      float mn = fmaxf(mrow, pm);
      float sc = exp2f(mrow - mn);
      lrow *= sc; mrow = mn;
      #pragma unroll
      for (int i = 0; i < 8; ++i) o[i] *= sc;
    }
    float p[16], sum = 0.f;
    #pragma unroll
    for (int r = 0; r < 16; ++r) { p[r] = exp2f(s4[r] - mrow); sum += p[r]; }
    lrow += sum + __shfl_xor(sum, 32, 64);

    // ---- P^T B-frags, lane-local: pack pairs, exchange halves, h-select
    uint32_t W[8], SW[8];
    #pragma unroll
    for (int i = 0; i < 8; ++i) W[i] = pk2(p[2 * i], p[2 * i + 1]);
    #pragma unroll
    for (int i = 0; i < 8; ++i) SW[i] = __shfl_xor(W[i], 32, 64);
    u32x4 f0, f1;
    if (hh == 0) {
      f0 = (u32x4){W[0], W[1], SW[0], SW[1]};   // kv 0..7
      f1 = (u32x4){W[4], W[5], SW[4], SW[5]};   // kv 16..23
    } else {
      f0 = (u32x4){SW[2], SW[3], W[2], W[3]};   // kv 8..15
      f1 = (u32x4){SW[6], SW[7], W[6], W[7]};   // kv 24..31
    }
    bf16x8 pb0 = __builtin_bit_cast(bf16x8, f0);
    bf16x8 pb1 = __builtin_bit_cast(bf16x8, f1);

    // ---- O^T += V^T P^T : V^T frags direct from L2 (16B/lane, rows 8KB apart)
    const char* vt = vLane + t * 64;
    #pragma unroll
    for (int db = 0; db < 8; ++db) {
      bf16x8 v0 = *(const bf16x8*)(vt + (size_t)db * 262144);
      bf16x8 v1 = *(const bf16x8*)(vt + (size_t)db * 262144 + 32);
      o[db] = __builtin_amdgcn_mfma_f32_32x32x16_bf16(v0, pb0, o[db], 0, 0, 0);
      o[db] = __builtin_amdgcn_mfma_f32_32x32x16_bf16(v1, pb1, o[db], 0, 0, 0);
    }

    __syncthreads();                 // all K reads of tile t done
    if (t < 63) STAGE(t + 1);        // DMA next tile (single buffer)
    __syncthreads();                 // vmcnt(0) drain -> tile t+1 visible
  }

  // ---- flash-merge: both halves write packed O^T to LDS (swizzled), m/l too
  {
    char* Ob = smem + hv * 16384;                  // [32 q][512B], ^ (q<<4)
    #pragma unroll
    for (int db = 0; db < 8; ++db)
      #pragma unroll
      for (int k = 0; k < 4; ++k) {
        uint32_t d2 = (uint32_t)(db * 64 + k * 16 + hh * 8);
        uint2 wv2;
        wv2.x = pk2(o[db][4 * k + 0], o[db][4 * k + 1]);
        wv2.y = pk2(o[db][4 * k + 2], o[db][4 * k + 3]);
        *(uint2*)(Ob + (uint32_t)l31 * 512 + (d2 ^ csw)) = wv2;
      }
    float* mls = (float*)(smem + 32768);           // [2][32][2]
    if (hh == 0) {
      mls[(hv * 32 + l31) * 2 + 0] = mrow;
      mls[(hv * 32 + l31) * 2 + 1] = lrow;
    }
  }
  __syncthreads();

  // ---- combine + coalesced store: thread t -> q = t>>2, 64-d chunk = (t&3)
  {
    const float* mls = (const float*)(smem + 32768);
    const int q = tid >> 2, c = tid & 3;
    float m0 = mls[q * 2], l0 = mls[q * 2 + 1];
    float m1 = mls[64 + q * 2], l1 = mls[64 + q * 2 + 1];
    float mn = fmaxf(m0, m1);
    float a0 = exp2f(m0 - mn), a1 = exp2f(m1 - mn);
    float inv = 1.f / (l0 * a0 + l1 * a1);
    a0 *= inv; a1 *= inv;
    float* op = out + (rowb + q0 + q) * 256;
    const uint32_t qs = (uint32_t)q << 4;
    #pragma unroll
    for (int j = 0; j < 8; ++j) {
      uint32_t d2 = (uint32_t)(c * 128 + 16 * j);
      uint4 u0 = *(const uint4*)(smem + (uint32_t)q * 512 + (d2 ^ qs));
      uint4 u1 = *(const uint4*)(smem + 16384 + (uint32_t)q * 512 + (d2 ^ qs));
      float4 r0, r1;
      r0.x = bf2f(u0.x & 0xffffu) * a0 + bf2f(u1.x & 0xffffu) * a1;
      r0.y = bf2f(u0.x >> 16)     * a0 + bf2f(u1.x >> 16)     * a1;
      r0.z = bf2f(u0.y & 0xffffu) * a0 + bf2f(u1.y & 0xffffu) * a1;
      r0.w = bf2f(u0.y >> 16)     * a0 + bf2f(u1.y >> 16)     * a1;
      r1.x = bf2f(u0.z & 0xffffu) * a0 + bf2f(u1.z & 0xffffu) * a1;
      r1.y = bf2f(u0.z >> 16)     * a0 + bf2f(u1.z >> 16)     * a1;
      r1.z = bf2f(u0.w & 0xffffu) * a0 + bf2f(u1.w & 0xffffu) * a1;
      r1.w = bf2f(u0.w >> 16)     * a0 + bf2f(u1.w >> 16)     * a1;
      *(float4*)(op + c * 64 + 8 * j) = r0;
      *(float4*)(op + c * 64 + 8 * j + 4) = r1;
    }
  }
}

// ---------------------------------------------------------------------------
extern "C" void kernel_launch(void* const* d_in, const int* in_sizes, int n_in,
                              void* d_out, int out_size, void* d_ws, size_t ws_size,
                              hipStream_t stream) {
  const float* xq = (const float*)d_in[0];
  const float* xk = (const float*)d_in[1];
  const float* xv = (const float*)d_in[2];
  // d_in[3] = mask (unused by reference forward)
  const float* wq = (const float*)d_in[4];
  const float* bq = (const float*)d_in[5];
  const float* wk = (const float*)d_in[6];
  const float* bk = (const float*)d_in[7];
  const float* wv = (const float*)d_in[8];
  const float* bv = (const float*)d_in[9];

  uint16_t* qws = (uint16_t*)d_ws;                       // [4][4096][256] bf16
  uint16_t* kws = qws + (size_t)4 * 4096 * 256;          // [4][4096][256] bf16
  uint16_t* vws = kws + (size_t)4 * 4096 * 256;          // [4][256][4096] bf16 (V^T)

  proj_kernel<<<dim3(128, 2, 3), 256, 0, stream>>>(
      xq, xk, xv, wq, wk, wv, bq, bk, bv, qws, kws, vws);

  (void)hipFuncSetAttribute((const void*)attn_kernel,
                            hipFuncAttributeMaxDynamicSharedMemorySize, 33280);
  attn_kernel<<<dim3(512), 128, 33280, stream>>>(qws, kws, vws, (float*)d_out);
}